// Round 1
// baseline (745.282 us; speedup 1.0000x reference)
//
#include <hip/hip_runtime.h>
#include <hip/hip_bf16.h>

#define NODES_DEFAULT 50000

// ---------------------------------------------------------------------------
// deg count: atomicAdd 1 per edge at dst
__global__ void k_deg(const int* __restrict__ dst, int* __restrict__ deg, int E) {
    int i = blockIdx.x * blockDim.x + threadIdx.x;
    if (i < E) atomicAdd(&deg[dst[i]], 1);
}

// dis[n] = deg>0 ? deg^-0.5 : 0
__global__ void k_dis(const int* __restrict__ deg, float* __restrict__ dis, int n) {
    int i = blockIdx.x * blockDim.x + threadIdx.x;
    if (i < n) {
        int d = deg[i];
        dis[i] = (d > 0) ? (1.0f / sqrtf((float)d)) : 0.0f;
    }
}

// single-block hierarchical exclusive scan of deg -> row_start (and cursor copy)
__global__ __launch_bounds__(1024) void k_scan(const int* __restrict__ deg,
                                               int* __restrict__ row_start,
                                               int* __restrict__ cursor, int n) {
    __shared__ int sWave[16];
    __shared__ int sCarry;
    const int tid = threadIdx.x;
    const int lane = tid & 63;
    const int wv = tid >> 6;
    if (tid == 0) sCarry = 0;
    __syncthreads();
    for (int base = 0; base < n; base += 1024) {
        int i = base + tid;
        int v = (i < n) ? deg[i] : 0;
        int x = v;
        #pragma unroll
        for (int off = 1; off < 64; off <<= 1) {
            int y = __shfl_up(x, off, 64);
            if (lane >= off) x += y;
        }
        if (lane == 63) sWave[wv] = x;
        __syncthreads();
        if (tid == 0) {
            int run = sCarry;
            #pragma unroll
            for (int w = 0; w < 16; ++w) { int t = sWave[w]; sWave[w] = run; run += t; }
            sCarry = run;
        }
        __syncthreads();
        if (i < n) { int ex = sWave[wv] + x - v; row_start[i] = ex; cursor[i] = ex; }
        __syncthreads();
    }
}

// scatter edges into CSR slots: csr[pos] = (src, bitcast(w))
__global__ void k_fill(const int* __restrict__ src, const int* __restrict__ dst,
                       const float* __restrict__ dis, int* __restrict__ cursor,
                       int2* __restrict__ csr, int E) {
    int e = blockIdx.x * blockDim.x + threadIdx.x;
    if (e >= E) return;
    int s = src[e], d = dst[e];
    int pos = atomicAdd(&cursor[d], 1);
    float w = dis[s] * dis[d];
    csr[pos] = make_int2(s, __float_as_int(w));
}

// pack w2 [4,128,32] -> Wc [128][128] with Wc[i][k*32+j] = w2[k][i][j]
__global__ void k_packw2(const float* __restrict__ w2, float* __restrict__ Wc) {
    int t = blockIdx.x * blockDim.x + threadIdx.x;
    if (t >= 128 * 128) return;
    int i = t >> 7, c = t & 127;
    int k = c >> 5, j = c & 31;
    Wc[t] = w2[(k * 128 + i) * 32 + j];
}

// ---------------------------------------------------------------------------
// GEMM: Out[n,0..127] = In[n,:128] @ W[128][128] (+Add[n,:]) (+Bias) (relu)
// block 256 threads; 64-row tile; thread = (tx: 4 cols, ty: 8 rows)
#define GEMM_TM 64
#define GEMM_TK 32
__global__ __launch_bounds__(256) void k_gemm128(
        const float* __restrict__ In, const float* __restrict__ W,
        const float* __restrict__ Add, const float* __restrict__ Bias,
        float* __restrict__ Out, int nrows, int relu) {
    __shared__ float sA[GEMM_TK][GEMM_TM + 4];   // transposed In chunk [k][row], pad 4
    __shared__ float sB[GEMM_TK][132];           // W chunk [k][col], pad 4
    const int tid = threadIdx.x;
    const int tx = tid & 31;     // cols tx*4 .. +3
    const int ty = tid >> 5;     // rows ty*8 .. +7
    const int rowBase = blockIdx.x * GEMM_TM;

    float acc[8][4];
    #pragma unroll
    for (int i = 0; i < 8; ++i)
        #pragma unroll
        for (int j = 0; j < 4; ++j) acc[i][j] = 0.0f;

    const int lr = tid >> 2;           // 0..63 row in tile
    const int lk = (tid & 3) * 8;      // k offset {0,8,16,24}
    const bool rowOK = (rowBase + lr) < nrows;
    const int bk = tid >> 3;           // 0..31
    const int bc = (tid & 7) * 16;     // col offset

    for (int k0 = 0; k0 < 128; k0 += GEMM_TK) {
        float4 a0 = make_float4(0, 0, 0, 0), a1 = a0;
        if (rowOK) {
            const float4* p = reinterpret_cast<const float4*>(
                In + (size_t)(rowBase + lr) * 128 + k0 + lk);
            a0 = p[0]; a1 = p[1];
        }
        const float4* pw = reinterpret_cast<const float4*>(
            W + (size_t)(k0 + bk) * 128 + bc);
        float4 b0 = pw[0], b1 = pw[1], b2 = pw[2], b3 = pw[3];
        __syncthreads();
        sA[lk + 0][lr] = a0.x; sA[lk + 1][lr] = a0.y;
        sA[lk + 2][lr] = a0.z; sA[lk + 3][lr] = a0.w;
        sA[lk + 4][lr] = a1.x; sA[lk + 5][lr] = a1.y;
        sA[lk + 6][lr] = a1.z; sA[lk + 7][lr] = a1.w;
        *reinterpret_cast<float4*>(&sB[bk][bc + 0])  = b0;
        *reinterpret_cast<float4*>(&sB[bk][bc + 4])  = b1;
        *reinterpret_cast<float4*>(&sB[bk][bc + 8])  = b2;
        *reinterpret_cast<float4*>(&sB[bk][bc + 12]) = b3;
        __syncthreads();
        #pragma unroll
        for (int kk = 0; kk < GEMM_TK; ++kk) {
            float4 b = *reinterpret_cast<const float4*>(&sB[kk][tx * 4]);
            float4 x0 = *reinterpret_cast<const float4*>(&sA[kk][ty * 8 + 0]);
            float4 x1 = *reinterpret_cast<const float4*>(&sA[kk][ty * 8 + 4]);
            float a[8] = {x0.x, x0.y, x0.z, x0.w, x1.x, x1.y, x1.z, x1.w};
            #pragma unroll
            for (int i = 0; i < 8; ++i) {
                acc[i][0] += a[i] * b.x; acc[i][1] += a[i] * b.y;
                acc[i][2] += a[i] * b.z; acc[i][3] += a[i] * b.w;
            }
        }
    }

    float4 bb = make_float4(0, 0, 0, 0);
    if (Bias) bb = *reinterpret_cast<const float4*>(Bias + tx * 4);
    #pragma unroll
    for (int i = 0; i < 8; ++i) {
        int r = rowBase + ty * 8 + i;
        if (r < nrows) {
            size_t off = (size_t)r * 128 + tx * 4;
            float4 v = make_float4(acc[i][0], acc[i][1], acc[i][2], acc[i][3]);
            if (Add) {
                float4 ad = *reinterpret_cast<const float4*>(Add + off);
                v.x += ad.x; v.y += ad.y; v.z += ad.z; v.w += ad.w;
            }
            v.x += bb.x; v.y += bb.y; v.z += bb.z; v.w += bb.w;
            if (relu) {
                v.x = fmaxf(v.x, 0.f); v.y = fmaxf(v.y, 0.f);
                v.z = fmaxf(v.z, 0.f); v.w = fmaxf(v.w, 0.f);
            }
            *reinterpret_cast<float4*>(Out + off) = v;
        }
    }
}

// ---------------------------------------------------------------------------
// 128-wide propagation (pull): one wave per node, lane = 2 features
__global__ __launch_bounds__(256) void k_prop128(
        const float* __restrict__ X, const int2* __restrict__ csr,
        const int* __restrict__ rs, const int* __restrict__ re,
        float* __restrict__ Out, int n) {
    int gw = (int)((blockIdx.x * (size_t)blockDim.x + threadIdx.x) >> 6);
    int lane = threadIdx.x & 63;
    if (gw >= n) return;
    int beg = rs[gw], end = re[gw];
    float2 acc = make_float2(0.f, 0.f);
    for (int e = beg; e < end; ++e) {
        int2 sw = csr[e];
        float w = __int_as_float(sw.y);
        float2 v = *reinterpret_cast<const float2*>(X + (size_t)sw.x * 128 + lane * 2);
        acc.x += w * v.x; acc.y += w * v.y;
    }
    *reinterpret_cast<float2*>(Out + (size_t)gw * 128 + lane * 2) = acc;
}

// 32-wide propagation + add of a G-slice (+bias):
// Out[n,j] = Gadd[n*128+goff+j] + bias[j] + sum_e w * X[src*xstride + xoff + j]
__global__ __launch_bounds__(256) void k_prop32(
        const float* __restrict__ X, int xoff, int xstride,
        const float* __restrict__ Gadd, int goff,
        const float* __restrict__ bias,
        const int2* __restrict__ csr, const int* __restrict__ rs,
        const int* __restrict__ re,
        float* __restrict__ Out, int ostride, int n) {
    int t = blockIdx.x * blockDim.x + threadIdx.x;
    int node = t >> 5, j = t & 31;
    if (node >= n) return;
    float acc = Gadd ? Gadd[(size_t)node * 128 + goff + j] : 0.0f;
    if (bias) acc += bias[j];
    int beg = rs[node], end = re[node];
    for (int e = beg; e < end; ++e) {
        int2 sw = csr[e];
        acc += __int_as_float(sw.y) * X[(size_t)sw.x * xstride + xoff + j];
    }
    Out[(size_t)node * ostride + j] = acc;
}

// ---------------------------------------------------------------------------
extern "C" void kernel_launch(void* const* d_in, const int* in_sizes, int n_in,
                              void* d_out, int out_size, void* d_ws, size_t ws_size,
                              hipStream_t stream) {
    const float* x  = (const float*)d_in[0];
    const int*   ei = (const int*)d_in[1];
    const float* w1 = (const float*)d_in[2];
    const float* b1 = (const float*)d_in[3];
    const float* w2 = (const float*)d_in[4];
    const float* b2 = (const float*)d_in[5];

    const int N = in_sizes[0] / 128;
    const int E = in_sizes[1] / 2;
    const int* srcIdx = ei;
    const int* dstIdx = ei + E;

    // workspace carve (16B aligned pieces)
    char* w = (char*)d_ws;
    int*   deg     = (int*)w;                       // N ints
    int*   rowst   = deg + N;                       // N ints
    int*   cursor  = rowst + N;                     // N ints (becomes row_end)
    float* dis     = (float*)(cursor + N);          // N floats
    int2*  csr     = (int2*)(dis + N);              // E int2
    float* Wc      = (float*)(csr + E);             // 128*128
    float* A1      = Wc + 128 * 128;                // N*128
    float* A2      = A1 + (size_t)N * 128;          // N*128
    float* H       = A2 + (size_t)N * 128;          // N*128
    float* S1      = A2;                            // reuse A2 (free after layer-1)
    float* S2      = A2 + (size_t)N * 32;

    hipMemsetAsync(deg, 0, (size_t)N * sizeof(int), stream);

    int eb = (E + 255) / 256;
    int nb = (N + 255) / 256;
    k_deg<<<eb, 256, 0, stream>>>(dstIdx, deg, E);
    k_dis<<<nb, 256, 0, stream>>>(deg, dis, N);
    k_scan<<<1, 1024, 0, stream>>>(deg, rowst, cursor, N);
    k_fill<<<eb, 256, 0, stream>>>(srcIdx, dstIdx, dis, cursor, csr, E);
    k_packw2<<<(128 * 128 + 255) / 256, 256, 0, stream>>>(w2, Wc);

    int gemmBlocks = (N + GEMM_TM - 1) / GEMM_TM;
    int propBlocks128 = (N * 64 + 255) / 256;   // wave per node
    int propBlocks32  = (N * 32 + 255) / 256;   // 32 threads per node

    // ---- layer 1 (Horner): h = relu(x@w0 + A(x@w1 + A(x@w2 + A(x@w3))) + b1)
    const size_t WSTRIDE1 = 128 * 128;
    k_gemm128<<<gemmBlocks, 256, 0, stream>>>(x, w1 + 3 * WSTRIDE1, nullptr, nullptr, A1, N, 0);
    k_prop128<<<propBlocks128, 256, 0, stream>>>(A1, csr, rowst, cursor, A2, N);
    k_gemm128<<<gemmBlocks, 256, 0, stream>>>(x, w1 + 2 * WSTRIDE1, A2, nullptr, A1, N, 0);
    k_prop128<<<propBlocks128, 256, 0, stream>>>(A1, csr, rowst, cursor, A2, N);
    k_gemm128<<<gemmBlocks, 256, 0, stream>>>(x, w1 + 1 * WSTRIDE1, A2, nullptr, A1, N, 0);
    k_prop128<<<propBlocks128, 256, 0, stream>>>(A1, csr, rowst, cursor, A2, N);
    k_gemm128<<<gemmBlocks, 256, 0, stream>>>(x, w1 + 0 * WSTRIDE1, A2, b1, H, N, 1);

    // ---- layer 2: G = H @ Wc (all 4 projections at once), then 32-wide Horner
    k_gemm128<<<gemmBlocks, 256, 0, stream>>>(H, Wc, nullptr, nullptr, A1, N, 0);
    // s1 = g2 + A g3
    k_prop32<<<propBlocks32, 256, 0, stream>>>(A1, 96, 128, A1, 64, nullptr,
                                               csr, rowst, cursor, S1, 32, N);
    // s2 = g1 + A s1
    k_prop32<<<propBlocks32, 256, 0, stream>>>(S1, 0, 32, A1, 32, nullptr,
                                               csr, rowst, cursor, S2, 32, N);
    // out = g0 + A s2 + b2
    k_prop32<<<propBlocks32, 256, 0, stream>>>(S2, 0, 32, A1, 0, b2,
                                               csr, rowst, cursor, (float*)d_out, 32, N);
}

// Round 2
// 436.804 us; speedup vs baseline: 1.7062x; 1.7062x over previous
//
#include <hip/hip_runtime.h>
#include <hip/hip_bf16.h>
#include <stdint.h>

typedef unsigned short u16;
typedef unsigned int u32;
using f32x4  = __attribute__((ext_vector_type(4))) float;
using bf16x8 = __attribute__((ext_vector_type(8))) short;

__device__ __forceinline__ float b2f(u16 u) {
    return __uint_as_float((u32)u << 16);
}
__device__ __forceinline__ u16 f2b(float f) {
    __hip_bfloat16 h = __float2bfloat16(f);
    return *reinterpret_cast<u16*>(&h);
}

// ---------------------------------------------------------------------------
// setup: degree, norm, CSR build (fp32)
__global__ void k_deg(const int* __restrict__ dst, int* __restrict__ deg, int E) {
    int i = blockIdx.x * blockDim.x + threadIdx.x;
    if (i < E) atomicAdd(&deg[dst[i]], 1);
}

__global__ void k_dis(const int* __restrict__ deg, float* __restrict__ dis, int n) {
    int i = blockIdx.x * blockDim.x + threadIdx.x;
    if (i < n) {
        int d = deg[i];
        dis[i] = (d > 0) ? (1.0f / sqrtf((float)d)) : 0.0f;
    }
}

__global__ __launch_bounds__(1024) void k_scan(const int* __restrict__ deg,
                                               int* __restrict__ row_start,
                                               int* __restrict__ cursor, int n) {
    __shared__ int sWave[16];
    __shared__ int sCarry;
    const int tid = threadIdx.x;
    const int lane = tid & 63;
    const int wv = tid >> 6;
    if (tid == 0) sCarry = 0;
    __syncthreads();
    for (int base = 0; base < n; base += 1024) {
        int i = base + tid;
        int v = (i < n) ? deg[i] : 0;
        int x = v;
        #pragma unroll
        for (int off = 1; off < 64; off <<= 1) {
            int y = __shfl_up(x, off, 64);
            if (lane >= off) x += y;
        }
        if (lane == 63) sWave[wv] = x;
        __syncthreads();
        if (tid == 0) {
            int run = sCarry;
            #pragma unroll
            for (int w = 0; w < 16; ++w) { int t = sWave[w]; sWave[w] = run; run += t; }
            sCarry = run;
        }
        __syncthreads();
        if (i < n) { int ex = sWave[wv] + x - v; row_start[i] = ex; cursor[i] = ex; }
        __syncthreads();
    }
}

__global__ void k_fill(const int* __restrict__ src, const int* __restrict__ dst,
                       const float* __restrict__ dis, int* __restrict__ cursor,
                       int2* __restrict__ csr, int E) {
    int e = blockIdx.x * blockDim.x + threadIdx.x;
    if (e >= E) return;
    int s = src[e], d = dst[e];
    int pos = atomicAdd(&cursor[d], 1);
    float w = dis[s] * dis[d];
    csr[pos] = make_int2(s, __float_as_int(w));
}

// ---------------------------------------------------------------------------
// convert x (fp32) -> bf16, zero pad rows [Nvalid, Mp)
__global__ void k_cvt_x(const float* __restrict__ x, u16* __restrict__ xb,
                        int Nvalid, int Mp) {
    int t = blockIdx.x * blockDim.x + threadIdx.x;
    size_t idx = (size_t)t * 4;
    if (idx >= (size_t)Mp * 128) return;
    int row = (int)(idx >> 7);
    u16 r[4];
    if (row < Nvalid) {
        float4 v = *reinterpret_cast<const float4*>(x + idx);
        r[0] = f2b(v.x); r[1] = f2b(v.y); r[2] = f2b(v.z); r[3] = f2b(v.w);
    } else {
        r[0] = r[1] = r[2] = r[3] = 0;
    }
    *reinterpret_cast<ushort4*>(xb + idx) = *reinterpret_cast<ushort4*>(r);
}

// pack W (fp32, [4][128][cw]) into MFMA B-fragment order, ncols = 4*cw
// frag f = nblock*4 + kstep; lane l holds B[kstep*32 + (l>>4)*8 + t][nblock*16 + (l&15)]
// where Bcat[kdim][kterm*cw + c] = W[kterm][kdim][c]
__global__ void k_packB(const float* __restrict__ W, u16* __restrict__ Bp,
                        int log2cw, int ncols) {
    int t = blockIdx.x * blockDim.x + threadIdx.x;
    int total = (ncols >> 4) * 4 * 64;
    if (t >= total) return;
    int lane = t & 63;
    int f = t >> 6;
    int ks = f & 3, nblock = f >> 2;
    int col = nblock * 16 + (lane & 15);
    int cw = 1 << log2cw;
    int kterm = col >> log2cw, c = col & (cw - 1);
    int kbase = ks * 32 + (lane >> 4) * 8;
    u16 out[8];
    #pragma unroll
    for (int i = 0; i < 8; ++i)
        out[i] = f2b(W[((size_t)kterm * 128 + (kbase + i)) * cw + c]);
    *reinterpret_cast<uint4*>(Bp + (size_t)t * 8) = *reinterpret_cast<uint4*>(out);
}

// ---------------------------------------------------------------------------
// MFMA GEMM: Out[Mp x ncols](bf16) = A[Mp x 128](bf16) @ B(packed frags)
// block = 4 waves, each wave: 32 rows x 128 cols; grid (Mp/128, ncols/128)
__global__ __launch_bounds__(256) void k_gemm_mfma(
        const u16* __restrict__ A, const u16* __restrict__ Bp,
        u16* __restrict__ Out, int Mvalid, int ncols) {
    const int lane = threadIdx.x & 63;
    const int wv = threadIdx.x >> 6;
    const int rowBase = blockIdx.x * 128 + wv * 32;
    const int colBase = blockIdx.y * 128;
    const int li = lane & 15, lh = lane >> 4;

    f32x4 acc[2][8];
    #pragma unroll
    for (int i = 0; i < 2; ++i)
        #pragma unroll
        for (int j = 0; j < 8; ++j)
            acc[i][j] = (f32x4){0.f, 0.f, 0.f, 0.f};

    #pragma unroll
    for (int ks = 0; ks < 4; ++ks) {
        bf16x8 a0 = *reinterpret_cast<const bf16x8*>(
            A + (size_t)(rowBase + li) * 128 + ks * 32 + lh * 8);
        bf16x8 a1 = *reinterpret_cast<const bf16x8*>(
            A + (size_t)(rowBase + 16 + li) * 128 + ks * 32 + lh * 8);
        #pragma unroll
        for (int nf = 0; nf < 8; ++nf) {
            const u16* pb = Bp + ((size_t)(((colBase >> 4) + nf) * 4 + ks) * 64 + lane) * 8;
            bf16x8 b = *reinterpret_cast<const bf16x8*>(pb);
            acc[0][nf] = __builtin_amdgcn_mfma_f32_16x16x32_bf16(a0, b, acc[0][nf], 0, 0, 0);
            acc[1][nf] = __builtin_amdgcn_mfma_f32_16x16x32_bf16(a1, b, acc[1][nf], 0, 0, 0);
        }
    }

    // D layout: col = lane&15, row = (lane>>4)*4 + reg   [m89]
    #pragma unroll
    for (int rg = 0; rg < 2; ++rg) {
        #pragma unroll
        for (int nf = 0; nf < 8; ++nf) {
            int col = colBase + nf * 16 + li;
            #pragma unroll
            for (int r = 0; r < 4; ++r) {
                int row = rowBase + rg * 16 + lh * 4 + r;
                if (row < Mvalid)
                    Out[(size_t)row * ncols + col] = f2b(acc[rg][nf][r]);
            }
        }
    }
}

// ---------------------------------------------------------------------------
// 128-wide propagation (bf16 gather, fp32 acc): wave per node, lane = 2 feats
// out = A*X[:, xoff:xoff+128] + Add[:, aoff:aoff+128] (+bias) (relu), bf16 out
__global__ __launch_bounds__(256) void k_prop_w(
        const u16* __restrict__ X, int xoff, int xstride,
        const u16* __restrict__ Add, int aoff, int astride,
        const float* __restrict__ bias, int relu,
        const int2* __restrict__ csr, const int* __restrict__ rs,
        const int* __restrict__ re,
        u16* __restrict__ Out, int ostride, int n) {
    int gw = (int)((blockIdx.x * (size_t)blockDim.x + threadIdx.x) >> 6);
    int lane = threadIdx.x & 63;
    if (gw >= n) return;
    const int fo = lane * 2;
    int beg = rs[gw], end = re[gw];
    float ax = 0.f, ay = 0.f;
    int e = beg;
    for (; e + 4 <= end; e += 4) {
        int2 c0 = csr[e], c1 = csr[e + 1], c2 = csr[e + 2], c3 = csr[e + 3];
        u32 u0 = *reinterpret_cast<const u32*>(X + (size_t)c0.x * xstride + xoff + fo);
        u32 u1 = *reinterpret_cast<const u32*>(X + (size_t)c1.x * xstride + xoff + fo);
        u32 u2 = *reinterpret_cast<const u32*>(X + (size_t)c2.x * xstride + xoff + fo);
        u32 u3 = *reinterpret_cast<const u32*>(X + (size_t)c3.x * xstride + xoff + fo);
        float w0 = __int_as_float(c0.y), w1 = __int_as_float(c1.y);
        float w2 = __int_as_float(c2.y), w3 = __int_as_float(c3.y);
        ax += w0 * b2f(u0 & 0xffff) + w1 * b2f(u1 & 0xffff)
            + w2 * b2f(u2 & 0xffff) + w3 * b2f(u3 & 0xffff);
        ay += w0 * b2f(u0 >> 16) + w1 * b2f(u1 >> 16)
            + w2 * b2f(u2 >> 16) + w3 * b2f(u3 >> 16);
    }
    for (; e < end; ++e) {
        int2 c = csr[e];
        u32 u = *reinterpret_cast<const u32*>(X + (size_t)c.x * xstride + xoff + fo);
        float w = __int_as_float(c.y);
        ax += w * b2f(u & 0xffff);
        ay += w * b2f(u >> 16);
    }
    if (Add) {
        u32 a = *reinterpret_cast<const u32*>(Add + (size_t)gw * astride + aoff + fo);
        ax += b2f(a & 0xffff);
        ay += b2f(a >> 16);
    }
    if (bias) { ax += bias[fo]; ay += bias[fo + 1]; }
    if (relu) { ax = fmaxf(ax, 0.f); ay = fmaxf(ay, 0.f); }
    u32 o = (u32)f2b(ax) | ((u32)f2b(ay) << 16);
    *reinterpret_cast<u32*>(Out + (size_t)gw * ostride + fo) = o;
}

// 32-wide propagation (bf16 gather, fp32 acc): 32 threads per node
__global__ __launch_bounds__(256) void k_prop_q(
        const u16* __restrict__ X, int xoff, int xstride,
        const u16* __restrict__ Add, int aoff, int astride,
        const float* __restrict__ bias,
        const int2* __restrict__ csr, const int* __restrict__ rs,
        const int* __restrict__ re,
        u16* __restrict__ OutB, float* __restrict__ OutF, int ostride, int n) {
    int t = blockIdx.x * blockDim.x + threadIdx.x;
    int node = t >> 5, j = t & 31;
    if (node >= n) return;
    float acc = 0.f;
    int beg = rs[node], end = re[node];
    int e = beg;
    for (; e + 4 <= end; e += 4) {
        int2 c0 = csr[e], c1 = csr[e + 1], c2 = csr[e + 2], c3 = csr[e + 3];
        float v0 = b2f(X[(size_t)c0.x * xstride + xoff + j]);
        float v1 = b2f(X[(size_t)c1.x * xstride + xoff + j]);
        float v2 = b2f(X[(size_t)c2.x * xstride + xoff + j]);
        float v3 = b2f(X[(size_t)c3.x * xstride + xoff + j]);
        acc += __int_as_float(c0.y) * v0 + __int_as_float(c1.y) * v1
             + __int_as_float(c2.y) * v2 + __int_as_float(c3.y) * v3;
    }
    for (; e < end; ++e) {
        int2 c = csr[e];
        acc += __int_as_float(c.y) * b2f(X[(size_t)c.x * xstride + xoff + j]);
    }
    if (Add) acc += b2f(Add[(size_t)node * astride + aoff + j]);
    if (bias) acc += bias[j];
    if (OutF) OutF[(size_t)node * ostride + j] = acc;
    else      OutB[(size_t)node * ostride + j] = f2b(acc);
}

// ---------------------------------------------------------------------------
static inline char* alignup(char* p, size_t a) {
    return (char*)(((uintptr_t)p + a - 1) & ~(uintptr_t)(a - 1));
}

extern "C" void kernel_launch(void* const* d_in, const int* in_sizes, int n_in,
                              void* d_out, int out_size, void* d_ws, size_t ws_size,
                              hipStream_t stream) {
    const float* x  = (const float*)d_in[0];
    const int*   ei = (const int*)d_in[1];
    const float* w1 = (const float*)d_in[2];
    const float* b1 = (const float*)d_in[3];
    const float* w2 = (const float*)d_in[4];
    const float* b2 = (const float*)d_in[5];

    const int N = in_sizes[0] / 128;
    const int E = in_sizes[1] / 2;
    const int Mp = ((N + 127) / 128) * 128;   // padded rows
    const int* srcIdx = ei;
    const int* dstIdx = ei + E;

    // workspace carve (256B aligned pieces)
    char* p = (char*)d_ws;
    int* deg    = (int*)p;                 p = alignup(p + (size_t)N * 4, 256);
    int* rowst  = (int*)p;                 p = alignup(p + (size_t)N * 4, 256);
    int* cursor = (int*)p;                 p = alignup(p + (size_t)N * 4, 256);
    float* dis  = (float*)p;               p = alignup(p + (size_t)N * 4, 256);
    int2* csr   = (int2*)p;                p = alignup(p + (size_t)E * 8, 256);
    u16* Bp1    = (u16*)p;                 p = alignup(p + (size_t)128 * 512 * 2, 256);
    u16* Bp2    = (u16*)p;                 p = alignup(p + (size_t)128 * 128 * 2, 256);
    u16* xb     = (u16*)p;                 p = alignup(p + (size_t)Mp * 128 * 2, 256);
    u16* G      = (u16*)p;                 p = alignup(p + (size_t)Mp * 512 * 2, 256);
    u16* t2     = (u16*)p;                 p = alignup(p + (size_t)Mp * 128 * 2, 256);
    u16* t1     = (u16*)p;                 p = alignup(p + (size_t)Mp * 128 * 2, 256);
    u16* h      = (u16*)p;                 p = alignup(p + (size_t)Mp * 128 * 2, 256);
    u16* Gc = G;          // reuse: G dead after h is computed
    u16* s1 = t2;         // reuse: t2 dead after h
    u16* s2 = t1;         // reuse: t1 dead after h

    hipMemsetAsync(deg, 0, (size_t)N * sizeof(int), stream);

    int eb = (E + 255) / 256;
    int nb = (N + 255) / 256;
    k_deg <<<eb, 256, 0, stream>>>(dstIdx, deg, E);
    k_dis <<<nb, 256, 0, stream>>>(deg, dis, N);
    k_scan<<<1, 1024, 0, stream>>>(deg, rowst, cursor, N);
    k_fill<<<eb, 256, 0, stream>>>(srcIdx, dstIdx, dis, cursor, csr, E);

    k_cvt_x<<<(Mp * 32 + 255) / 256, 256, 0, stream>>>(x, xb, N, Mp);
    k_packB<<<(8192 + 255) / 256, 256, 0, stream>>>(w1, Bp1, 7, 512);
    k_packB<<<(2048 + 255) / 256, 256, 0, stream>>>(w2, Bp2, 5, 128);

    const int gw = Mp / 128;
    const int pb128 = (N * 64 + 255) / 256;
    const int pb32  = (N * 32 + 255) / 256;

    // ---- layer 1: G = x @ [W3|W2|W1|W0... ordered k-major] (cols k*128..)
    k_gemm_mfma<<<dim3(gw, 4), 256, 0, stream>>>(xb, Bp1, G, N, 512);
    // Horner: t2 = A*G3 + G2 ; t1 = A*t2 + G1 ; h = relu(A*t1 + G0 + b1)
    k_prop_w<<<pb128, 256, 0, stream>>>(G, 384, 512, G, 256, 512, nullptr, 0,
                                        csr, rowst, cursor, t2, 128, N);
    k_prop_w<<<pb128, 256, 0, stream>>>(t2, 0, 128, G, 128, 512, nullptr, 0,
                                        csr, rowst, cursor, t1, 128, N);
    k_prop_w<<<pb128, 256, 0, stream>>>(t1, 0, 128, G, 0, 512, b1, 1,
                                        csr, rowst, cursor, h, 128, N);

    // ---- layer 2: Gc = h @ [V3|V2|V1|V0] (cols k*32..), then 32-wide Horner
    k_gemm_mfma<<<dim3(gw, 1), 256, 0, stream>>>(h, Bp2, Gc, N, 128);
    k_prop_q<<<pb32, 256, 0, stream>>>(Gc, 96, 128, Gc, 64, 128, nullptr,
                                       csr, rowst, cursor, s1, nullptr, 32, N);
    k_prop_q<<<pb32, 256, 0, stream>>>(s1, 0, 32, Gc, 32, 128, nullptr,
                                       csr, rowst, cursor, s2, nullptr, 32, N);
    k_prop_q<<<pb32, 256, 0, stream>>>(s2, 0, 32, Gc, 0, 128, b2,
                                       csr, rowst, cursor, nullptr, (float*)d_out, 32, N);
}

// Round 3
// 407.846 us; speedup vs baseline: 1.8274x; 1.0710x over previous
//
#include <hip/hip_runtime.h>
#include <hip/hip_bf16.h>
#include <stdint.h>

typedef unsigned short u16;
typedef unsigned int u32;
using f32x4  = __attribute__((ext_vector_type(4))) float;
using bf16x8 = __attribute__((ext_vector_type(8))) short;

__device__ __forceinline__ float b2f(u16 u) {
    return __uint_as_float((u32)u << 16);
}
__device__ __forceinline__ u16 f2b(float f) {
    __hip_bfloat16 h = __float2bfloat16(f);
    return *reinterpret_cast<u16*>(&h);
}

// ---------------------------------------------------------------------------
// setup: degree count
__global__ void k_deg(const int* __restrict__ dst, int* __restrict__ deg, int E) {
    int i = blockIdx.x * blockDim.x + threadIdx.x;
    if (i < E) atomicAdd(&deg[dst[i]], 1);
}

// per-block partial sums over 4096-element chunks
#define SCAN_CHUNK 4096
__global__ __launch_bounds__(1024) void k_bsum(const int* __restrict__ deg,
                                               int* __restrict__ bsum, int n) {
    int base = blockIdx.x * SCAN_CHUNK + threadIdx.x * 4;
    int s = 0;
    if (base + 3 < n) {
        int4 v = *reinterpret_cast<const int4*>(deg + base);
        s = v.x + v.y + v.z + v.w;
    } else {
        #pragma unroll
        for (int j = 0; j < 4; ++j) if (base + j < n) s += deg[base + j];
    }
    #pragma unroll
    for (int off = 32; off; off >>= 1) s += __shfl_down(s, off, 64);
    __shared__ int sW[16];
    int lane = threadIdx.x & 63, wv = threadIdx.x >> 6;
    if (lane == 0) sW[wv] = s;
    __syncthreads();
    if (threadIdx.x == 0) {
        int t = 0;
        #pragma unroll
        for (int w = 0; w < 16; ++w) t += sW[w];
        bsum[blockIdx.x] = t;
    }
}

// per-block exclusive scan + cross-block offset (redundant small prefix);
// also emits dis = deg^-0.5
__global__ __launch_bounds__(1024) void k_scan2(const int* __restrict__ deg,
        const int* __restrict__ bsum,
        int* __restrict__ row_start, int* __restrict__ cursor,
        float* __restrict__ dis, int n) {
    const int tid = threadIdx.x, lane = tid & 63, wv = tid >> 6;
    const int base = blockIdx.x * SCAN_CHUNK + tid * 4;
    int v0 = 0, v1 = 0, v2 = 0, v3 = 0;
    if (base + 3 < n) {
        int4 v = *reinterpret_cast<const int4*>(deg + base);
        v0 = v.x; v1 = v.y; v2 = v.z; v3 = v.w;
    } else {
        if (base + 0 < n) v0 = deg[base + 0];
        if (base + 1 < n) v1 = deg[base + 1];
        if (base + 2 < n) v2 = deg[base + 2];
        if (base + 3 < n) v3 = deg[base + 3];
    }
    const int s = v0 + v1 + v2 + v3;
    int x = s;
    #pragma unroll
    for (int off = 1; off < 64; off <<= 1) {
        int y = __shfl_up(x, off, 64);
        if (lane >= off) x += y;
    }
    __shared__ int sW[16];
    if (lane == 63) sW[wv] = x;
    __syncthreads();
    if (tid == 0) {
        int run = 0;
        #pragma unroll
        for (int w = 0; w < 16; ++w) { int t = sW[w]; sW[w] = run; run += t; }
    }
    __syncthreads();
    int boff = 0;
    for (int b = 0; b < blockIdx.x; ++b) boff += bsum[b];   // uniform, <=12 iters
    int run = boff + sW[wv] + (x - s);
    if (base + 0 < n) { row_start[base+0]=run; cursor[base+0]=run;
                        dis[base+0] = v0>0 ? 1.0f/sqrtf((float)v0) : 0.0f; run += v0; }
    if (base + 1 < n) { row_start[base+1]=run; cursor[base+1]=run;
                        dis[base+1] = v1>0 ? 1.0f/sqrtf((float)v1) : 0.0f; run += v1; }
    if (base + 2 < n) { row_start[base+2]=run; cursor[base+2]=run;
                        dis[base+2] = v2>0 ? 1.0f/sqrtf((float)v2) : 0.0f; run += v2; }
    if (base + 3 < n) { row_start[base+3]=run; cursor[base+3]=run;
                        dis[base+3] = v3>0 ? 1.0f/sqrtf((float)v3) : 0.0f; }
}

__global__ void k_fill(const int* __restrict__ src, const int* __restrict__ dst,
                       const float* __restrict__ dis, int* __restrict__ cursor,
                       int2* __restrict__ csr, int E) {
    int e = blockIdx.x * blockDim.x + threadIdx.x;
    if (e >= E) return;
    int s = src[e], d = dst[e];
    int pos = atomicAdd(&cursor[d], 1);
    float w = dis[s] * dis[d];
    csr[pos] = make_int2(s, __float_as_int(w));
}

// ---------------------------------------------------------------------------
// convert x (fp32) -> bf16, zero pad rows [Nvalid, Mp)
__global__ void k_cvt_x(const float* __restrict__ x, u16* __restrict__ xb,
                        int Nvalid, int Mp) {
    int t = blockIdx.x * blockDim.x + threadIdx.x;
    size_t idx = (size_t)t * 4;
    if (idx >= (size_t)Mp * 128) return;
    int row = (int)(idx >> 7);
    u16 r[4];
    if (row < Nvalid) {
        float4 v = *reinterpret_cast<const float4*>(x + idx);
        r[0] = f2b(v.x); r[1] = f2b(v.y); r[2] = f2b(v.z); r[3] = f2b(v.w);
    } else {
        r[0] = r[1] = r[2] = r[3] = 0;
    }
    *reinterpret_cast<ushort4*>(xb + idx) = *reinterpret_cast<ushort4*>(r);
}

// pack W (fp32, [4][128][cw]) into MFMA B-fragment order, ncols = 4*cw
__global__ void k_packB(const float* __restrict__ W, u16* __restrict__ Bp,
                        int log2cw, int ncols) {
    int t = blockIdx.x * blockDim.x + threadIdx.x;
    int total = (ncols >> 4) * 4 * 64;
    if (t >= total) return;
    int lane = t & 63;
    int f = t >> 6;
    int ks = f & 3, nblock = f >> 2;
    int col = nblock * 16 + (lane & 15);
    int cw = 1 << log2cw;
    int kterm = col >> log2cw, c = col & (cw - 1);
    int kbase = ks * 32 + (lane >> 4) * 8;
    u16 out[8];
    #pragma unroll
    for (int i = 0; i < 8; ++i)
        out[i] = f2b(W[((size_t)kterm * 128 + (kbase + i)) * cw + c]);
    *reinterpret_cast<uint4*>(Bp + (size_t)t * 8) = *reinterpret_cast<uint4*>(out);
}

// ---------------------------------------------------------------------------
// MFMA GEMM: Out[Mp x ncols](bf16) = A[Mp x 128](bf16) @ B(packed frags)
__global__ __launch_bounds__(256) void k_gemm_mfma(
        const u16* __restrict__ A, const u16* __restrict__ Bp,
        u16* __restrict__ Out, int Mvalid, int ncols) {
    const int lane = threadIdx.x & 63;
    const int wv = threadIdx.x >> 6;
    const int rowBase = blockIdx.x * 128 + wv * 32;
    const int colBase = blockIdx.y * 128;
    const int li = lane & 15, lh = lane >> 4;

    f32x4 acc[2][8];
    #pragma unroll
    for (int i = 0; i < 2; ++i)
        #pragma unroll
        for (int j = 0; j < 8; ++j)
            acc[i][j] = (f32x4){0.f, 0.f, 0.f, 0.f};

    #pragma unroll
    for (int ks = 0; ks < 4; ++ks) {
        bf16x8 a0 = *reinterpret_cast<const bf16x8*>(
            A + (size_t)(rowBase + li) * 128 + ks * 32 + lh * 8);
        bf16x8 a1 = *reinterpret_cast<const bf16x8*>(
            A + (size_t)(rowBase + 16 + li) * 128 + ks * 32 + lh * 8);
        #pragma unroll
        for (int nf = 0; nf < 8; ++nf) {
            const u16* pb = Bp + ((size_t)(((colBase >> 4) + nf) * 4 + ks) * 64 + lane) * 8;
            bf16x8 b = *reinterpret_cast<const bf16x8*>(pb);
            acc[0][nf] = __builtin_amdgcn_mfma_f32_16x16x32_bf16(a0, b, acc[0][nf], 0, 0, 0);
            acc[1][nf] = __builtin_amdgcn_mfma_f32_16x16x32_bf16(a1, b, acc[1][nf], 0, 0, 0);
        }
    }

    // D layout: col = lane&15, row = (lane>>4)*4 + reg   [m89]
    #pragma unroll
    for (int rg = 0; rg < 2; ++rg) {
        #pragma unroll
        for (int nf = 0; nf < 8; ++nf) {
            int col = colBase + nf * 16 + li;
            #pragma unroll
            for (int r = 0; r < 4; ++r) {
                int row = rowBase + rg * 16 + lh * 4 + r;
                if (row < Mvalid)
                    Out[(size_t)row * ncols + col] = f2b(acc[rg][nf][r]);
            }
        }
    }
}

// ---------------------------------------------------------------------------
// 128-wide propagation (bf16 gather, fp32 acc): wave per node, lane = 2 feats
// out = A*X[:, xoff:] + Add[:, aoff:] (+bias) (relu), bf16 out. NT streams.
__global__ __launch_bounds__(256) void k_prop_w(
        const u16* __restrict__ X, int xoff, int xstride,
        const u16* __restrict__ Add, int aoff, int astride,
        const float* __restrict__ bias, int relu,
        const int2* __restrict__ csr, const int* __restrict__ rs,
        const int* __restrict__ re,
        u16* __restrict__ Out, int ostride, int n) {
    int gw = (int)((blockIdx.x * (size_t)blockDim.x + threadIdx.x) >> 6);
    int lane = threadIdx.x & 63;
    if (gw >= n) return;
    const int fo = lane * 2;
    const u16* Xb = X + xoff + fo;
    int beg = rs[gw], end = re[gw];
    float ax = 0.f, ay = 0.f, bx = 0.f, by = 0.f;
    int e = beg;
    for (; e + 8 <= end; e += 8) {
        int2 c[8];
        #pragma unroll
        for (int j = 0; j < 8; ++j) c[j] = csr[e + j];
        u32 u[8];
        #pragma unroll
        for (int j = 0; j < 8; ++j)
            u[j] = *reinterpret_cast<const u32*>(Xb + (size_t)c[j].x * xstride);
        #pragma unroll
        for (int j = 0; j < 8; ++j) {
            float w = __int_as_float(c[j].y);
            if (j & 1) { bx += w * b2f(u[j] & 0xffff); by += w * b2f(u[j] >> 16); }
            else       { ax += w * b2f(u[j] & 0xffff); ay += w * b2f(u[j] >> 16); }
        }
    }
    for (; e < end; ++e) {
        int2 c = csr[e];
        u32 u = *reinterpret_cast<const u32*>(Xb + (size_t)c.x * xstride);
        float w = __int_as_float(c.y);
        ax += w * b2f(u & 0xffff);
        ay += w * b2f(u >> 16);
    }
    ax += bx; ay += by;
    if (Add) {
        u32 a = __builtin_nontemporal_load(
            reinterpret_cast<const u32*>(Add + (size_t)gw * astride + aoff + fo));
        ax += b2f(a & 0xffff);
        ay += b2f(a >> 16);
    }
    if (bias) { ax += bias[fo]; ay += bias[fo + 1]; }
    if (relu) { ax = fmaxf(ax, 0.f); ay = fmaxf(ay, 0.f); }
    u32 o = (u32)f2b(ax) | ((u32)f2b(ay) << 16);
    __builtin_nontemporal_store(o, reinterpret_cast<u32*>(Out + (size_t)gw * ostride + fo));
}

// 32-wide propagation (bf16 gather, fp32 acc): 32 threads per node
__global__ __launch_bounds__(256) void k_prop_q(
        const u16* __restrict__ X, int xoff, int xstride,
        const u16* __restrict__ Add, int aoff, int astride,
        const float* __restrict__ bias,
        const int2* __restrict__ csr, const int* __restrict__ rs,
        const int* __restrict__ re,
        u16* __restrict__ OutB, float* __restrict__ OutF, int ostride, int n) {
    int t = blockIdx.x * blockDim.x + threadIdx.x;
    int node = t >> 5, j = t & 31;
    if (node >= n) return;
    const u16* Xb = X + xoff + j;
    float acc = 0.f, acc2 = 0.f;
    int beg = rs[node], end = re[node];
    int e = beg;
    for (; e + 8 <= end; e += 8) {
        int2 c[8];
        #pragma unroll
        for (int q = 0; q < 8; ++q) c[q] = csr[e + q];
        float v[8];
        #pragma unroll
        for (int q = 0; q < 8; ++q) v[q] = b2f(Xb[(size_t)c[q].x * xstride]);
        #pragma unroll
        for (int q = 0; q < 8; ++q) {
            if (q & 1) acc2 += __int_as_float(c[q].y) * v[q];
            else       acc  += __int_as_float(c[q].y) * v[q];
        }
    }
    for (; e < end; ++e) {
        int2 c = csr[e];
        acc += __int_as_float(c.y) * b2f(Xb[(size_t)c.x * xstride]);
    }
    acc += acc2;
    if (Add) acc += b2f(__builtin_nontemporal_load(Add + (size_t)node * astride + aoff + j));
    if (bias) acc += bias[j];
    if (OutF) __builtin_nontemporal_store(acc, OutF + (size_t)node * ostride + j);
    else      __builtin_nontemporal_store(f2b(acc), OutB + (size_t)node * ostride + j);
}

// ---------------------------------------------------------------------------
static inline char* alignup(char* p, size_t a) {
    return (char*)(((uintptr_t)p + a - 1) & ~(uintptr_t)(a - 1));
}

extern "C" void kernel_launch(void* const* d_in, const int* in_sizes, int n_in,
                              void* d_out, int out_size, void* d_ws, size_t ws_size,
                              hipStream_t stream) {
    const float* x  = (const float*)d_in[0];
    const int*   ei = (const int*)d_in[1];
    const float* w1 = (const float*)d_in[2];
    const float* b1 = (const float*)d_in[3];
    const float* w2 = (const float*)d_in[4];
    const float* b2 = (const float*)d_in[5];

    const int N = in_sizes[0] / 128;
    const int E = in_sizes[1] / 2;
    const int Mp = ((N + 127) / 128) * 128;
    const int* srcIdx = ei;
    const int* dstIdx = ei + E;

    // workspace carve (256B aligned pieces)
    char* p = (char*)d_ws;
    int* deg    = (int*)p;                 p = alignup(p + (size_t)N * 4, 256);
    int* rowst  = (int*)p;                 p = alignup(p + (size_t)N * 4, 256);
    int* cursor = (int*)p;                 p = alignup(p + (size_t)N * 4, 256);
    float* dis  = (float*)p;               p = alignup(p + (size_t)N * 4, 256);
    int* bsum   = (int*)p;                 p = alignup(p + 64 * 4, 256);
    int2* csr   = (int2*)p;                p = alignup(p + (size_t)E * 8, 256);
    u16* Bp1    = (u16*)p;                 p = alignup(p + (size_t)128 * 512 * 2, 256);
    u16* Bp2    = (u16*)p;                 p = alignup(p + (size_t)128 * 128 * 2, 256);
    u16* xb     = (u16*)p;                 p = alignup(p + (size_t)Mp * 128 * 2, 256);
    u16* G      = (u16*)p;                 p = alignup(p + (size_t)Mp * 512 * 2, 256);
    u16* t2     = (u16*)p;                 p = alignup(p + (size_t)Mp * 128 * 2, 256);
    u16* t1     = (u16*)p;                 p = alignup(p + (size_t)Mp * 128 * 2, 256);
    u16* h      = (u16*)p;                 p = alignup(p + (size_t)Mp * 128 * 2, 256);
    u16* Gc = G;
    u16* s1 = t2;
    u16* s2 = t1;

    hipMemsetAsync(deg, 0, (size_t)N * sizeof(int), stream);

    const int eb = (E + 255) / 256;
    const int scanBlocks = (N + SCAN_CHUNK - 1) / SCAN_CHUNK;

    k_deg  <<<eb, 256, 0, stream>>>(dstIdx, deg, E);
    k_bsum <<<scanBlocks, 1024, 0, stream>>>(deg, bsum, N);
    k_scan2<<<scanBlocks, 1024, 0, stream>>>(deg, bsum, rowst, cursor, dis, N);
    k_fill <<<eb, 256, 0, stream>>>(srcIdx, dstIdx, dis, cursor, csr, E);

    k_cvt_x<<<(Mp * 32 + 255) / 256, 256, 0, stream>>>(x, xb, N, Mp);
    k_packB<<<(8192 + 255) / 256, 256, 0, stream>>>(w1, Bp1, 7, 512);
    k_packB<<<(2048 + 255) / 256, 256, 0, stream>>>(w2, Bp2, 5, 128);

    const int gw = Mp / 128;
    const int pb128 = (N * 64 + 255) / 256;
    const int pb32  = (N * 32 + 255) / 256;

    // ---- layer 1: G = x @ [W0|W1|W2|W3] (cols k*128..)
    k_gemm_mfma<<<dim3(gw, 4), 256, 0, stream>>>(xb, Bp1, G, N, 512);
    // Horner: t2 = A*G3 + G2 ; t1 = A*t2 + G1 ; h = relu(A*t1 + G0 + b1)
    k_prop_w<<<pb128, 256, 0, stream>>>(G, 384, 512, G, 256, 512, nullptr, 0,
                                        csr, rowst, cursor, t2, 128, N);
    k_prop_w<<<pb128, 256, 0, stream>>>(t2, 0, 128, G, 128, 512, nullptr, 0,
                                        csr, rowst, cursor, t1, 128, N);
    k_prop_w<<<pb128, 256, 0, stream>>>(t1, 0, 128, G, 0, 512, b1, 1,
                                        csr, rowst, cursor, h, 128, N);

    // ---- layer 2: Gc = h @ [V0|V1|V2|V3] (cols k*32..), then 32-wide Horner
    k_gemm_mfma<<<dim3(gw, 1), 256, 0, stream>>>(h, Bp2, Gc, N, 128);
    k_prop_q<<<pb32, 256, 0, stream>>>(Gc, 96, 128, Gc, 64, 128, nullptr,
                                       csr, rowst, cursor, s1, nullptr, 32, N);
    k_prop_q<<<pb32, 256, 0, stream>>>(s1, 0, 32, Gc, 32, 128, nullptr,
                                       csr, rowst, cursor, s2, nullptr, 32, N);
    k_prop_q<<<pb32, 256, 0, stream>>>(s2, 0, 32, Gc, 0, 128, b2,
                                       csr, rowst, cursor, nullptr, (float*)d_out, 32, N);
}

// Round 4
// 360.248 us; speedup vs baseline: 2.0688x; 1.1321x over previous
//
#include <hip/hip_runtime.h>
#include <hip/hip_bf16.h>
#include <stdint.h>

typedef unsigned short u16;
typedef unsigned int u32;
using f32x4  = __attribute__((ext_vector_type(4))) float;
using bf16x8 = __attribute__((ext_vector_type(8))) short;

__device__ __forceinline__ float b2f(u16 u) {
    return __uint_as_float((u32)u << 16);
}
__device__ __forceinline__ u16 f2b(float f) {
    __hip_bfloat16 h = __float2bfloat16(f);
    return *reinterpret_cast<u16*>(&h);
}
__device__ __forceinline__ short f2bs(float f) {
    return (short)f2b(f);
}

// ---------------------------------------------------------------------------
// degree count
__global__ void k_deg(const int* __restrict__ dst, int* __restrict__ deg, int E) {
    int i = blockIdx.x * blockDim.x + threadIdx.x;
    if (i < E) atomicAdd(&deg[dst[i]], 1);
}

// per-block partial sums of PADDED degrees over 4096-element chunks
#define SCAN_CHUNK 4096
__device__ __forceinline__ int padd8(int d) { return (d + 7) & ~7; }

__global__ __launch_bounds__(1024) void k_bsum(const int* __restrict__ deg,
                                               int* __restrict__ bsum, int n) {
    int base = blockIdx.x * SCAN_CHUNK + threadIdx.x * 4;
    int s = 0;
    if (base + 3 < n) {
        int4 v = *reinterpret_cast<const int4*>(deg + base);
        s = padd8(v.x) + padd8(v.y) + padd8(v.z) + padd8(v.w);
    } else {
        #pragma unroll
        for (int j = 0; j < 4; ++j) if (base + j < n) s += padd8(deg[base + j]);
    }
    #pragma unroll
    for (int off = 32; off; off >>= 1) s += __shfl_down(s, off, 64);
    __shared__ int sW[16];
    int lane = threadIdx.x & 63, wv = threadIdx.x >> 6;
    if (lane == 0) sW[wv] = s;
    __syncthreads();
    if (threadIdx.x == 0) {
        int t = 0;
        #pragma unroll
        for (int w = 0; w < 16; ++w) t += sW[w];
        bsum[blockIdx.x] = t;
    }
}

// per-block exclusive scan of padded degrees + cross-block offset; emits dis
__global__ __launch_bounds__(1024) void k_scan2(const int* __restrict__ deg,
        const int* __restrict__ bsum,
        int* __restrict__ row_start, int* __restrict__ cursor,
        float* __restrict__ dis, int n) {
    const int tid = threadIdx.x, lane = tid & 63, wv = tid >> 6;
    const int base = blockIdx.x * SCAN_CHUNK + tid * 4;
    int v0 = 0, v1 = 0, v2 = 0, v3 = 0;
    if (base + 3 < n) {
        int4 v = *reinterpret_cast<const int4*>(deg + base);
        v0 = v.x; v1 = v.y; v2 = v.z; v3 = v.w;
    } else {
        if (base + 0 < n) v0 = deg[base + 0];
        if (base + 1 < n) v1 = deg[base + 1];
        if (base + 2 < n) v2 = deg[base + 2];
        if (base + 3 < n) v3 = deg[base + 3];
    }
    const int p0 = padd8(v0), p1 = padd8(v1), p2 = padd8(v2), p3 = padd8(v3);
    const int s = p0 + p1 + p2 + p3;
    int x = s;
    #pragma unroll
    for (int off = 1; off < 64; off <<= 1) {
        int y = __shfl_up(x, off, 64);
        if (lane >= off) x += y;
    }
    __shared__ int sW[16];
    if (lane == 63) sW[wv] = x;
    __syncthreads();
    if (tid == 0) {
        int run = 0;
        #pragma unroll
        for (int w = 0; w < 16; ++w) { int t = sW[w]; sW[w] = run; run += t; }
    }
    __syncthreads();
    int boff = 0;
    for (int b = 0; b < blockIdx.x; ++b) boff += bsum[b];   // uniform, <=12 iters
    int run = boff + sW[wv] + (x - s);
    if (base + 0 < n) { row_start[base+0]=run; cursor[base+0]=run;
                        dis[base+0] = v0>0 ? 1.0f/sqrtf((float)v0) : 0.0f; run += p0; }
    if (base + 1 < n) { row_start[base+1]=run; cursor[base+1]=run;
                        dis[base+1] = v1>0 ? 1.0f/sqrtf((float)v1) : 0.0f; run += p1; }
    if (base + 2 < n) { row_start[base+2]=run; cursor[base+2]=run;
                        dis[base+2] = v2>0 ? 1.0f/sqrtf((float)v2) : 0.0f; run += p2; }
    if (base + 3 < n) { row_start[base+3]=run; cursor[base+3]=run;
                        dis[base+3] = v3>0 ? 1.0f/sqrtf((float)v3) : 0.0f; }
}

// scatter edges: csr[pos] = (src*256 bytes, w)
__global__ void k_fill(const int* __restrict__ src, const int* __restrict__ dst,
                       const float* __restrict__ dis, int* __restrict__ cursor,
                       int2* __restrict__ csr, int E) {
    int e = blockIdx.x * blockDim.x + threadIdx.x;
    if (e >= E) return;
    int s = src[e], d = dst[e];
    int pos = atomicAdd(&cursor[d], 1);
    float w = dis[s] * dis[d];
    csr[pos] = make_int2(s << 8, __float_as_int(w));
}

// pad each row to multiple of 8 with (0, 0.0f); set cursor = padded end
__global__ void k_pad(const int* __restrict__ rs, int* __restrict__ cursor,
                      int2* __restrict__ csr, int n) {
    int i = blockIdx.x * blockDim.x + threadIdx.x;
    if (i >= n) return;
    int beg = rs[i];
    int end = cursor[i];
    int pend = beg + padd8(end - beg);
    for (int e = end; e < pend; ++e) csr[e] = make_int2(0, 0);
    cursor[i] = pend;
}

// ---------------------------------------------------------------------------
// pack both weight tensors into MFMA B-fragment order
// w1: [4][128][128] -> Bp1 (8192 frag-lanes); w2: [4][128][32] -> Bp2 (2048)
__global__ void k_packBoth(const float* __restrict__ w1, const float* __restrict__ w2,
                           u16* __restrict__ Bp1, u16* __restrict__ Bp2) {
    int t = blockIdx.x * blockDim.x + threadIdx.x;
    const float* W; u16* Bp; int log2cw; int tt;
    if (t < 8192)        { W = w1; Bp = Bp1; log2cw = 7; tt = t; }
    else if (t < 10240)  { W = w2; Bp = Bp2; log2cw = 5; tt = t - 8192; }
    else return;
    int lane = tt & 63;
    int f = tt >> 6;
    int ks = f & 3, nblock = f >> 2;
    int col = nblock * 16 + (lane & 15);
    int cw = 1 << log2cw;
    int kterm = col >> log2cw, c = col & (cw - 1);
    int kbase = ks * 32 + (lane >> 4) * 8;
    u16 out[8];
    #pragma unroll
    for (int i = 0; i < 8; ++i)
        out[i] = f2b(W[((size_t)kterm * 128 + (kbase + i)) * cw + c]);
    *reinterpret_cast<uint4*>(Bp + (size_t)tt * 8) = *reinterpret_cast<uint4*>(out);
}

// ---------------------------------------------------------------------------
// MFMA GEMM, A kept in registers across ncb column-blocks of 128.
// Out block cb -> Out + cb*outStride, each [row][128] bf16 (canonical 256B rows)
// A_FP32: A is fp32 [Mp][128]; else bf16 [Mp][128].
template<int A_FP32>
__global__ __launch_bounds__(256) void k_gemm(
        const void* __restrict__ Av, const u16* __restrict__ Bp,
        u16* __restrict__ Out, size_t outStride, int ncb, int Mvalid) {
    const int lane = threadIdx.x & 63;
    const int wv = threadIdx.x >> 6;
    const int rowBase = blockIdx.x * 128 + wv * 32;
    const int li = lane & 15, lh = lane >> 4;

    // load A fragments once: 2 row-groups x 4 k-steps
    bf16x8 a[2][4];
    #pragma unroll
    for (int rg = 0; rg < 2; ++rg) {
        int r = rowBase + rg * 16 + li;
        bool ok = (r < Mvalid);
        #pragma unroll
        for (int ks = 0; ks < 4; ++ks) {
            if (A_FP32) {
                const float* A = (const float*)Av;
                bf16x8 v = {0,0,0,0,0,0,0,0};
                if (ok) {
                    const float* p = A + (size_t)r * 128 + ks * 32 + lh * 8;
                    float4 f0 = *reinterpret_cast<const float4*>(p);
                    float4 f1 = *reinterpret_cast<const float4*>(p + 4);
                    v[0] = f2bs(f0.x); v[1] = f2bs(f0.y);
                    v[2] = f2bs(f0.z); v[3] = f2bs(f0.w);
                    v[4] = f2bs(f1.x); v[5] = f2bs(f1.y);
                    v[6] = f2bs(f1.z); v[7] = f2bs(f1.w);
                }
                a[rg][ks] = v;
            } else {
                const u16* A = (const u16*)Av;
                bf16x8 v = {0,0,0,0,0,0,0,0};
                if (ok)
                    v = *reinterpret_cast<const bf16x8*>(A + (size_t)r * 128 + ks * 32 + lh * 8);
                a[rg][ks] = v;
            }
        }
    }

    for (int cb = 0; cb < ncb; ++cb) {
        f32x4 acc[2][8];
        #pragma unroll
        for (int i = 0; i < 2; ++i)
            #pragma unroll
            for (int j = 0; j < 8; ++j)
                acc[i][j] = (f32x4){0.f, 0.f, 0.f, 0.f};
        #pragma unroll
        for (int ks = 0; ks < 4; ++ks) {
            #pragma unroll
            for (int nf = 0; nf < 8; ++nf) {
                const u16* pb = Bp + ((size_t)((cb * 8 + nf) * 4 + ks) * 64 + lane) * 8;
                bf16x8 b = *reinterpret_cast<const bf16x8*>(pb);
                acc[0][nf] = __builtin_amdgcn_mfma_f32_16x16x32_bf16(a[0][ks], b, acc[0][nf], 0, 0, 0);
                acc[1][nf] = __builtin_amdgcn_mfma_f32_16x16x32_bf16(a[1][ks], b, acc[1][nf], 0, 0, 0);
            }
        }
        // D layout: col = lane&15, row = (lane>>4)*4 + reg   [m89]
        u16* Ob = Out + (size_t)cb * outStride;
        #pragma unroll
        for (int rg = 0; rg < 2; ++rg) {
            #pragma unroll
            for (int nf = 0; nf < 8; ++nf) {
                int col = nf * 16 + li;
                #pragma unroll
                for (int r = 0; r < 4; ++r) {
                    int row = rowBase + rg * 16 + lh * 4 + r;
                    if (row < Mvalid)
                        Ob[(size_t)row * 128 + col] = f2b(acc[rg][nf][r]);
                }
            }
        }
    }
}

// ---------------------------------------------------------------------------
// 128-wide propagation (canonical 256B rows, byte-offset csr, padded rows):
// out = A*X + Add (+bias) (relu), bf16 out. Wave per node, lane = 2 feats.
__global__ __launch_bounds__(256) void k_prop_w(
        const u16* __restrict__ X,
        const u16* __restrict__ Add,
        const float* __restrict__ bias, int relu,
        const int2* __restrict__ csr, const int* __restrict__ rs,
        const int* __restrict__ re,
        u16* __restrict__ Out, int n) {
    int gw = (int)((blockIdx.x * (size_t)blockDim.x + threadIdx.x) >> 6);
    int lane = threadIdx.x & 63;
    if (gw >= n) return;
    const char* Xb = (const char*)X + lane * 4;
    int beg = rs[gw], end = re[gw];
    float ax = 0.f, ay = 0.f, bx = 0.f, by = 0.f;
    for (int e = beg; e < end; e += 8) {
        int2 c[8];
        #pragma unroll
        for (int j = 0; j < 8; ++j) c[j] = csr[e + j];
        u32 u[8];
        #pragma unroll
        for (int j = 0; j < 8; ++j)
            u[j] = *reinterpret_cast<const u32*>(Xb + (size_t)(u32)c[j].x);
        #pragma unroll
        for (int j = 0; j < 8; ++j) {
            float w = __int_as_float(c[j].y);
            if (j & 1) { bx += w * b2f(u[j] & 0xffff); by += w * b2f(u[j] >> 16); }
            else       { ax += w * b2f(u[j] & 0xffff); ay += w * b2f(u[j] >> 16); }
        }
    }
    ax += bx; ay += by;
    const int fo = lane * 2;
    if (Add) {
        u32 a = __builtin_nontemporal_load(
            reinterpret_cast<const u32*>(Add + (size_t)gw * 128 + fo));
        ax += b2f(a & 0xffff);
        ay += b2f(a >> 16);
    }
    if (bias) { ax += bias[fo]; ay += bias[fo + 1]; }
    if (relu) { ax = fmaxf(ax, 0.f); ay = fmaxf(ay, 0.f); }
    u32 o = (u32)f2b(ax) | ((u32)f2b(ay) << 16);
    __builtin_nontemporal_store(o, reinterpret_cast<u32*>(Out + (size_t)gw * 128 + fo));
}

// 32-wide propagation: 32 threads per node; X rows 256B>>rsh; padded rows.
__global__ __launch_bounds__(256) void k_prop_q(
        const u16* __restrict__ X, int xoffB, int rsh,
        const u16* __restrict__ Add,
        const float* __restrict__ bias,
        const int2* __restrict__ csr, const int* __restrict__ rs,
        const int* __restrict__ re,
        u16* __restrict__ OutB, float* __restrict__ OutF, int n) {
    int t = blockIdx.x * blockDim.x + threadIdx.x;
    int node = t >> 5, j = t & 31;
    if (node >= n) return;
    const char* Xb = (const char*)X + xoffB + j * 2;
    float acc = 0.f, acc2 = 0.f;
    int beg = rs[node], end = re[node];
    for (int e = beg; e < end; e += 8) {
        int2 c[8];
        #pragma unroll
        for (int q = 0; q < 8; ++q) c[q] = csr[e + q];
        float v[8];
        #pragma unroll
        for (int q = 0; q < 8; ++q)
            v[q] = b2f(*reinterpret_cast<const u16*>(Xb + ((size_t)(u32)c[q].x >> rsh)));
        #pragma unroll
        for (int q = 0; q < 8; ++q) {
            if (q & 1) acc2 += __int_as_float(c[q].y) * v[q];
            else       acc  += __int_as_float(c[q].y) * v[q];
        }
    }
    acc += acc2;
    if (Add) acc += b2f(__builtin_nontemporal_load(Add + (size_t)node * 128 + j));
    if (bias) acc += bias[j];
    if (OutF) __builtin_nontemporal_store(acc, OutF + (size_t)node * 32 + j);
    else      __builtin_nontemporal_store(f2b(acc), OutB + (size_t)node * 32 + j);
}

// ---------------------------------------------------------------------------
static inline char* alignup(char* p, size_t a) {
    return (char*)(((uintptr_t)p + a - 1) & ~(uintptr_t)(a - 1));
}

extern "C" void kernel_launch(void* const* d_in, const int* in_sizes, int n_in,
                              void* d_out, int out_size, void* d_ws, size_t ws_size,
                              hipStream_t stream) {
    const float* x  = (const float*)d_in[0];
    const int*   ei = (const int*)d_in[1];
    const float* w1 = (const float*)d_in[2];
    const float* b1 = (const float*)d_in[3];
    const float* w2 = (const float*)d_in[4];
    const float* b2 = (const float*)d_in[5];

    const int N = in_sizes[0] / 128;
    const int E = in_sizes[1] / 2;
    const int Mp = ((N + 127) / 128) * 128;
    const int* srcIdx = ei;
    const int* dstIdx = ei + E;

    // workspace carve (256B aligned pieces)
    char* p = (char*)d_ws;
    int* deg    = (int*)p;                 p = alignup(p + (size_t)N * 4, 256);
    int* rowst  = (int*)p;                 p = alignup(p + (size_t)N * 4, 256);
    int* cursor = (int*)p;                 p = alignup(p + (size_t)N * 4, 256);
    float* dis  = (float*)p;               p = alignup(p + (size_t)N * 4, 256);
    int* bsum   = (int*)p;                 p = alignup(p + 64 * 4, 256);
    int2* csr   = (int2*)p;                p = alignup(p + ((size_t)E + 8 * (size_t)N) * 8, 256);
    u16* Bp1    = (u16*)p;                 p = alignup(p + (size_t)128 * 512 * 2, 256);
    u16* Bp2    = (u16*)p;                 p = alignup(p + (size_t)128 * 128 * 2, 256);
    u16* G      = (u16*)p;                 p = alignup(p + (size_t)Mp * 512 * 2, 256);  // 4 canonical bufs
    u16* t2     = (u16*)p;                 p = alignup(p + (size_t)Mp * 128 * 2, 256);
    u16* t1     = (u16*)p;                 p = alignup(p + (size_t)Mp * 128 * 2, 256);
    u16* h      = (u16*)p;                 p = alignup(p + (size_t)Mp * 128 * 2, 256);
    const size_t GS = (size_t)Mp * 128;    // per-buffer stride
    u16* Gc = G;                            // reuse G0 region after layer 1
    u16* s1 = t2;
    u16* s2 = t1;

    hipMemsetAsync(deg, 0, (size_t)N * sizeof(int), stream);

    const int eb = (E + 255) / 256;
    const int nb = (N + 255) / 256;
    const int scanBlocks = (N + SCAN_CHUNK - 1) / SCAN_CHUNK;

    k_deg  <<<eb, 256, 0, stream>>>(dstIdx, deg, E);
    k_bsum <<<scanBlocks, 1024, 0, stream>>>(deg, bsum, N);
    k_scan2<<<scanBlocks, 1024, 0, stream>>>(deg, bsum, rowst, cursor, dis, N);
    k_fill <<<eb, 256, 0, stream>>>(srcIdx, dstIdx, dis, cursor, csr, E);
    k_pad  <<<nb, 256, 0, stream>>>(rowst, cursor, csr, N);
    k_packBoth<<<(10240 + 255) / 256, 256, 0, stream>>>(w1, w2, Bp1, Bp2);

    const int gb = Mp / 128;
    const int pb128 = (N * 64 + 255) / 256;
    const int pb32  = (N * 32 + 255) / 256;

    // ---- layer 1: Gk = x @ W1_k (4 canonical buffers), fused fp32->bf16
    k_gemm<1><<<gb, 256, 0, stream>>>(x, Bp1, G, GS, 4, N);
    // Horner: t2 = A*G3 + G2 ; t1 = A*t2 + G1 ; h = relu(A*t1 + G0 + b1)
    k_prop_w<<<pb128, 256, 0, stream>>>(G + 3 * GS, G + 2 * GS, nullptr, 0,
                                        csr, rowst, cursor, t2, N);
    k_prop_w<<<pb128, 256, 0, stream>>>(t2, G + 1 * GS, nullptr, 0,
                                        csr, rowst, cursor, t1, N);
    k_prop_w<<<pb128, 256, 0, stream>>>(t1, G + 0 * GS, b1, 1,
                                        csr, rowst, cursor, h, N);

    // ---- layer 2: Gc = h @ [V0|V1|V2|V3] (128 cols), then 32-wide Horner
    k_gemm<0><<<gb, 256, 0, stream>>>(h, Bp2, Gc, GS, 1, N);
    k_prop_q<<<pb32, 256, 0, stream>>>(Gc, 192, 0, Gc + 64, nullptr,
                                       csr, rowst, cursor, s1, nullptr, N);
    k_prop_q<<<pb32, 256, 0, stream>>>(s1, 0, 2, Gc + 32, nullptr,
                                       csr, rowst, cursor, s2, nullptr, N);
    k_prop_q<<<pb32, 256, 0, stream>>>(s2, 0, 2, Gc, b2,
                                       csr, rowst, cursor, nullptr, (float*)d_out, N);
}

// Round 5
// 320.616 us; speedup vs baseline: 2.3245x; 1.1236x over previous
//
#include <hip/hip_runtime.h>
#include <hip/hip_bf16.h>
#include <stdint.h>

typedef unsigned short u16;
typedef unsigned int u32;
using f32x4  = __attribute__((ext_vector_type(4))) float;
using bf16x8 = __attribute__((ext_vector_type(8))) short;

__device__ __forceinline__ float b2f(u16 u) {
    return __uint_as_float((u32)u << 16);
}
__device__ __forceinline__ u16 f2b(float f) {
    __hip_bfloat16 h = __float2bfloat16(f);
    return *reinterpret_cast<u16*>(&h);
}
__device__ __forceinline__ short f2bs(float f) {
    return (short)f2b(f);
}
__device__ __forceinline__ int padd8(int d) { return (d + 7) & ~7; }

// ---------------------------------------------------------------------------
// Bucketed CSR build. Bucket = 512 consecutive dst nodes (dst>>9).
// Keeps all scattered csr writes single-block-owned (one XCD's L2) to kill
// the 8x cross-XCD partial-line write-back amplification seen in k_fill.
#define BSH 9
#define BNODES (1 << BSH)
#define BCAP 16384          // stage capacity per bucket (mean 8.2k, +91 sigma)

// partition edges into buckets; stage entry = (src<<9) | (dst&511)
__global__ __launch_bounds__(256) void k_part(
        const int* __restrict__ src, const int* __restrict__ dst, int E,
        int* __restrict__ gCnt, u32* __restrict__ stage) {
    __shared__ int hist[128];
    __shared__ int runBase[128];
    const int tid = threadIdx.x;
    if (tid < 128) hist[tid] = 0;
    __syncthreads();
    const int base = blockIdx.x * 1024 + tid * 4;
    int s[4], d[4], bk[4], rk[4];
    bool ok[4];
    if (base + 3 < E) {
        int4 sv = *reinterpret_cast<const int4*>(src + base);
        int4 dv = *reinterpret_cast<const int4*>(dst + base);
        s[0]=sv.x; s[1]=sv.y; s[2]=sv.z; s[3]=sv.w;
        d[0]=dv.x; d[1]=dv.y; d[2]=dv.z; d[3]=dv.w;
        ok[0]=ok[1]=ok[2]=ok[3]=true;
    } else {
        #pragma unroll
        for (int j = 0; j < 4; ++j) {
            ok[j] = (base + j) < E;
            s[j] = ok[j] ? src[base + j] : 0;
            d[j] = ok[j] ? dst[base + j] : 0;
        }
    }
    #pragma unroll
    for (int j = 0; j < 4; ++j)
        if (ok[j]) { bk[j] = d[j] >> BSH; rk[j] = atomicAdd(&hist[bk[j]], 1); }
    __syncthreads();
    if (tid < 128) {
        int c = hist[tid];
        runBase[tid] = c ? atomicAdd(&gCnt[tid], c) : 0;
    }
    __syncthreads();
    #pragma unroll
    for (int j = 0; j < 4; ++j)
        if (ok[j])
            stage[(size_t)bk[j] * BCAP + runBase[bk[j]] + rk[j]] =
                ((u32)s[j] << BSH) | (u32)(d[j] & (BNODES - 1));
}

// per bucket: histogram -> dis (deg^-0.5) + padded-size total
__global__ __launch_bounds__(256) void k_b1(
        const u32* __restrict__ stage, const int* __restrict__ gCnt,
        float* __restrict__ dis, int* __restrict__ bucketPad, int N) {
    __shared__ int hist[BNODES];
    __shared__ int sW[4];
    const int b = blockIdx.x, tid = threadIdx.x;
    for (int i = tid; i < BNODES; i += 256) hist[i] = 0;
    __syncthreads();
    const int cnt = gCnt[b];
    const u32* st = stage + (size_t)b * BCAP;
    for (int e = tid; e < cnt; e += 256)
        atomicAdd(&hist[st[e] & (BNODES - 1)], 1);
    __syncthreads();
    const int nbase = b << BSH;
    int ps = 0;
    for (int i = tid; i < BNODES; i += 256) {
        int node = nbase + i;
        if (node < N) {
            int dg = hist[i];
            dis[node] = dg > 0 ? (1.0f / sqrtf((float)dg)) : 0.0f;
            ps += padd8(dg);
        }
    }
    #pragma unroll
    for (int off = 32; off; off >>= 1) ps += __shfl_down(ps, off, 64);
    int lane = tid & 63, wv = tid >> 6;
    if (lane == 0) sW[wv] = ps;
    __syncthreads();
    if (tid == 0) bucketPad[b] = sW[0] + sW[1] + sW[2] + sW[3];
}

// per bucket: re-histogram + scan -> rowst/rowend + pad + csr fill (LDS atomics)
__global__ __launch_bounds__(256) void k_b2(
        const u32* __restrict__ stage, const int* __restrict__ gCnt,
        const int* __restrict__ bucketPad, const float* __restrict__ dis,
        int* __restrict__ rowst, int* __restrict__ rowend,
        int2* __restrict__ csr, int N) {
    __shared__ int hist[BNODES];
    __shared__ int lofs[BNODES];
    __shared__ int cur[BNODES];
    __shared__ int sW[4];
    const int b = blockIdx.x, tid = threadIdx.x;
    for (int i = tid; i < BNODES; i += 256) hist[i] = 0;
    __syncthreads();
    const int cnt = gCnt[b];
    const u32* st = stage + (size_t)b * BCAP;
    for (int e = tid; e < cnt; e += 256)
        atomicAdd(&hist[st[e] & (BNODES - 1)], 1);
    __syncthreads();
    // exclusive scan of padded degrees (2 elements per thread)
    const int i0 = tid * 2, i1 = tid * 2 + 1;
    const int p0 = padd8(hist[i0]), p1 = padd8(hist[i1]);
    const int sps = p0 + p1;
    int x = sps;
    #pragma unroll
    for (int off = 1; off < 64; off <<= 1) {
        int y = __shfl_up(x, off, 64);
        if ((tid & 63) >= off) x += y;
    }
    int lane = tid & 63, wv = tid >> 6;
    if (lane == 63) sW[wv] = x;
    __syncthreads();
    if (tid == 0) {
        int run = 0;
        #pragma unroll
        for (int w = 0; w < 4; ++w) { int t = sW[w]; sW[w] = run; run += t; }
    }
    __syncthreads();
    const int excl = sW[wv] + (x - sps);
    lofs[i0] = excl;
    lofs[i1] = excl + p0;
    // cross-bucket base (uniform small loop; dispatch boundary ordered b1->b2)
    int boff = 0;
    for (int bb = 0; bb < b; ++bb) boff += bucketPad[bb];
    __syncthreads();
    const int nbase = b << BSH;
    for (int i = tid; i < BNODES; i += 256) {
        cur[i] = lofs[i];
        int node = nbase + i;
        if (node < N) {
            int dg = hist[i];
            int rsG = boff + lofs[i];
            rowst[node] = rsG;
            rowend[node] = rsG + padd8(dg);
            for (int e = dg; e < padd8(dg); ++e)
                csr[rsG + e] = make_int2(0, 0);
        }
    }
    __syncthreads();
    for (int e = tid; e < cnt; e += 256) {
        u32 sd = st[e];
        int ld = sd & (BNODES - 1);
        int s = (int)(sd >> BSH);
        int lpos = atomicAdd(&cur[ld], 1);
        float w = dis[s] * dis[nbase + ld];
        csr[boff + lpos] = make_int2(s << 8, __float_as_int(w));
    }
}

// ---------------------------------------------------------------------------
// pack both weight tensors into MFMA B-fragment order
__global__ void k_packBoth(const float* __restrict__ w1, const float* __restrict__ w2,
                           u16* __restrict__ Bp1, u16* __restrict__ Bp2) {
    int t = blockIdx.x * blockDim.x + threadIdx.x;
    const float* W; u16* Bp; int log2cw; int tt;
    if (t < 8192)        { W = w1; Bp = Bp1; log2cw = 7; tt = t; }
    else if (t < 10240)  { W = w2; Bp = Bp2; log2cw = 5; tt = t - 8192; }
    else return;
    int lane = tt & 63;
    int f = tt >> 6;
    int ks = f & 3, nblock = f >> 2;
    int col = nblock * 16 + (lane & 15);
    int cw = 1 << log2cw;
    int kterm = col >> log2cw, c = col & (cw - 1);
    int kbase = ks * 32 + (lane >> 4) * 8;
    u16 out[8];
    #pragma unroll
    for (int i = 0; i < 8; ++i)
        out[i] = f2b(W[((size_t)kterm * 128 + (kbase + i)) * cw + c]);
    *reinterpret_cast<uint4*>(Bp + (size_t)tt * 8) = *reinterpret_cast<uint4*>(out);
}

// ---------------------------------------------------------------------------
// MFMA GEMM, A kept in registers across ncb column-blocks of 128.
template<int A_FP32>
__global__ __launch_bounds__(256) void k_gemm(
        const void* __restrict__ Av, const u16* __restrict__ Bp,
        u16* __restrict__ Out, size_t outStride, int ncb, int Mvalid) {
    const int lane = threadIdx.x & 63;
    const int wv = threadIdx.x >> 6;
    const int rowBase = blockIdx.x * 128 + wv * 32;
    const int li = lane & 15, lh = lane >> 4;

    bf16x8 a[2][4];
    #pragma unroll
    for (int rg = 0; rg < 2; ++rg) {
        int r = rowBase + rg * 16 + li;
        bool ok = (r < Mvalid);
        #pragma unroll
        for (int ks = 0; ks < 4; ++ks) {
            if (A_FP32) {
                const float* A = (const float*)Av;
                bf16x8 v = {0,0,0,0,0,0,0,0};
                if (ok) {
                    const float* p = A + (size_t)r * 128 + ks * 32 + lh * 8;
                    float4 f0 = *reinterpret_cast<const float4*>(p);
                    float4 f1 = *reinterpret_cast<const float4*>(p + 4);
                    v[0] = f2bs(f0.x); v[1] = f2bs(f0.y);
                    v[2] = f2bs(f0.z); v[3] = f2bs(f0.w);
                    v[4] = f2bs(f1.x); v[5] = f2bs(f1.y);
                    v[6] = f2bs(f1.z); v[7] = f2bs(f1.w);
                }
                a[rg][ks] = v;
            } else {
                const u16* A = (const u16*)Av;
                bf16x8 v = {0,0,0,0,0,0,0,0};
                if (ok)
                    v = *reinterpret_cast<const bf16x8*>(A + (size_t)r * 128 + ks * 32 + lh * 8);
                a[rg][ks] = v;
            }
        }
    }

    for (int cb = 0; cb < ncb; ++cb) {
        f32x4 acc[2][8];
        #pragma unroll
        for (int i = 0; i < 2; ++i)
            #pragma unroll
            for (int j = 0; j < 8; ++j)
                acc[i][j] = (f32x4){0.f, 0.f, 0.f, 0.f};
        #pragma unroll
        for (int ks = 0; ks < 4; ++ks) {
            #pragma unroll
            for (int nf = 0; nf < 8; ++nf) {
                const u16* pb = Bp + ((size_t)((cb * 8 + nf) * 4 + ks) * 64 + lane) * 8;
                bf16x8 bfr = *reinterpret_cast<const bf16x8*>(pb);
                acc[0][nf] = __builtin_amdgcn_mfma_f32_16x16x32_bf16(a[0][ks], bfr, acc[0][nf], 0, 0, 0);
                acc[1][nf] = __builtin_amdgcn_mfma_f32_16x16x32_bf16(a[1][ks], bfr, acc[1][nf], 0, 0, 0);
            }
        }
        // D layout: col = lane&15, row = (lane>>4)*4 + reg   [m89]
        u16* Ob = Out + (size_t)cb * outStride;
        #pragma unroll
        for (int rg = 0; rg < 2; ++rg) {
            #pragma unroll
            for (int nf = 0; nf < 8; ++nf) {
                int col = nf * 16 + li;
                #pragma unroll
                for (int r = 0; r < 4; ++r) {
                    int row = rowBase + rg * 16 + lh * 4 + r;
                    if (row < Mvalid)
                        Ob[(size_t)row * 128 + col] = f2b(acc[rg][nf][r]);
                }
            }
        }
    }
}

// ---------------------------------------------------------------------------
// 128-wide propagation (canonical 256B rows, byte-offset csr, padded rows)
__global__ __launch_bounds__(256) void k_prop_w(
        const u16* __restrict__ X,
        const u16* __restrict__ Add,
        const float* __restrict__ bias, int relu,
        const int2* __restrict__ csr, const int* __restrict__ rs,
        const int* __restrict__ re,
        u16* __restrict__ Out, int n) {
    int gw = (int)((blockIdx.x * (size_t)blockDim.x + threadIdx.x) >> 6);
    int lane = threadIdx.x & 63;
    if (gw >= n) return;
    const char* Xb = (const char*)X + lane * 4;
    int beg = rs[gw], end = re[gw];
    float ax = 0.f, ay = 0.f, bx = 0.f, by = 0.f;
    for (int e = beg; e < end; e += 8) {
        int2 c[8];
        #pragma unroll
        for (int j = 0; j < 8; ++j) c[j] = csr[e + j];
        u32 u[8];
        #pragma unroll
        for (int j = 0; j < 8; ++j)
            u[j] = *reinterpret_cast<const u32*>(Xb + (size_t)(u32)c[j].x);
        #pragma unroll
        for (int j = 0; j < 8; ++j) {
            float w = __int_as_float(c[j].y);
            if (j & 1) { bx += w * b2f(u[j] & 0xffff); by += w * b2f(u[j] >> 16); }
            else       { ax += w * b2f(u[j] & 0xffff); ay += w * b2f(u[j] >> 16); }
        }
    }
    ax += bx; ay += by;
    const int fo = lane * 2;
    if (Add) {
        u32 a = __builtin_nontemporal_load(
            reinterpret_cast<const u32*>(Add + (size_t)gw * 128 + fo));
        ax += b2f(a & 0xffff);
        ay += b2f(a >> 16);
    }
    if (bias) { ax += bias[fo]; ay += bias[fo + 1]; }
    if (relu) { ax = fmaxf(ax, 0.f); ay = fmaxf(ay, 0.f); }
    u32 o = (u32)f2b(ax) | ((u32)f2b(ay) << 16);
    __builtin_nontemporal_store(o, reinterpret_cast<u32*>(Out + (size_t)gw * 128 + fo));
}

// 32-wide propagation: 32 threads per node; X rows 256B>>rsh; padded rows.
__global__ __launch_bounds__(256) void k_prop_q(
        const u16* __restrict__ X, int xoffB, int rsh,
        const u16* __restrict__ Add,
        const float* __restrict__ bias,
        const int2* __restrict__ csr, const int* __restrict__ rs,
        const int* __restrict__ re,
        u16* __restrict__ OutB, float* __restrict__ OutF, int n) {
    int t = blockIdx.x * blockDim.x + threadIdx.x;
    int node = t >> 5, j = t & 31;
    if (node >= n) return;
    const char* Xb = (const char*)X + xoffB + j * 2;
    float acc = 0.f, acc2 = 0.f;
    int beg = rs[node], end = re[node];
    for (int e = beg; e < end; e += 8) {
        int2 c[8];
        #pragma unroll
        for (int q = 0; q < 8; ++q) c[q] = csr[e + q];
        float v[8];
        #pragma unroll
        for (int q = 0; q < 8; ++q)
            v[q] = b2f(*reinterpret_cast<const u16*>(Xb + ((size_t)(u32)c[q].x >> rsh)));
        #pragma unroll
        for (int q = 0; q < 8; ++q) {
            if (q & 1) acc2 += __int_as_float(c[q].y) * v[q];
            else       acc  += __int_as_float(c[q].y) * v[q];
        }
    }
    acc += acc2;
    if (Add) acc += b2f(__builtin_nontemporal_load(Add + (size_t)node * 128 + j));
    if (bias) acc += bias[j];
    if (OutF) __builtin_nontemporal_store(acc, OutF + (size_t)node * 32 + j);
    else      __builtin_nontemporal_store(f2b(acc), OutB + (size_t)node * 32 + j);
}

// ---------------------------------------------------------------------------
static inline char* alignup(char* p, size_t a) {
    return (char*)(((uintptr_t)p + a - 1) & ~(uintptr_t)(a - 1));
}

extern "C" void kernel_launch(void* const* d_in, const int* in_sizes, int n_in,
                              void* d_out, int out_size, void* d_ws, size_t ws_size,
                              hipStream_t stream) {
    const float* x  = (const float*)d_in[0];
    const int*   ei = (const int*)d_in[1];
    const float* w1 = (const float*)d_in[2];
    const float* b1 = (const float*)d_in[3];
    const float* w2 = (const float*)d_in[4];
    const float* b2 = (const float*)d_in[5];

    const int N = in_sizes[0] / 128;
    const int E = in_sizes[1] / 2;
    const int Mp = ((N + 127) / 128) * 128;
    const int NBK = (N + BNODES - 1) >> BSH;     // buckets (98 for N=50000)
    const int* srcIdx = ei;
    const int* dstIdx = ei + E;

    // workspace carve (256B aligned pieces)
    char* p = (char*)d_ws;
    int* rowst  = (int*)p;                 p = alignup(p + (size_t)N * 4, 256);
    int* rowend = (int*)p;                 p = alignup(p + (size_t)N * 4, 256);
    float* dis  = (float*)p;               p = alignup(p + (size_t)N * 4, 256);
    int* gCnt   = (int*)p;                 p = alignup(p + 128 * 4, 256);
    int* bucketPad = (int*)p;              p = alignup(p + 128 * 4, 256);
    int2* csr   = (int2*)p;                p = alignup(p + ((size_t)E + 8 * (size_t)N) * 8, 256);
    u16* Bp1    = (u16*)p;                 p = alignup(p + (size_t)128 * 512 * 2, 256);
    u16* Bp2    = (u16*)p;                 p = alignup(p + (size_t)128 * 128 * 2, 256);
    u16* G      = (u16*)p;                 p = alignup(p + (size_t)Mp * 512 * 2, 256);
    const size_t GS = (size_t)Mp * 128;
    // t2 region doubles as the partition stage buffer (dead until prop#1)
    size_t t2Bytes = GS * 2, stageBytes = (size_t)NBK * BCAP * 4;
    size_t u = t2Bytes > stageBytes ? t2Bytes : stageBytes;
    u16* t2     = (u16*)p;
    u32* stage  = (u32*)p;                 p = alignup(p + u, 256);
    u16* t1     = (u16*)p;                 p = alignup(p + GS * 2, 256);
    u16* h      = (u16*)p;                 p = alignup(p + GS * 2, 256);
    u16* Gc = G;
    u16* s1 = t2;
    u16* s2 = t1;

    hipMemsetAsync(gCnt, 0, 128 * sizeof(int), stream);

    // ---- CSR build (bucketed counting sort)
    k_part<<<(E + 1023) / 1024, 256, 0, stream>>>(srcIdx, dstIdx, E, gCnt, stage);
    k_b1  <<<NBK, 256, 0, stream>>>(stage, gCnt, dis, bucketPad, N);
    k_b2  <<<NBK, 256, 0, stream>>>(stage, gCnt, bucketPad, dis, rowst, rowend, csr, N);
    k_packBoth<<<(10240 + 255) / 256, 256, 0, stream>>>(w1, w2, Bp1, Bp2);

    const int gb = Mp / 128;
    const int pb128 = (N * 64 + 255) / 256;
    const int pb32  = (N * 32 + 255) / 256;

    // ---- layer 1: Gk = x @ W1_k (4 canonical buffers), fused fp32->bf16
    k_gemm<1><<<gb, 256, 0, stream>>>(x, Bp1, G, GS, 4, N);
    // Horner: t2 = A*G3 + G2 ; t1 = A*t2 + G1 ; h = relu(A*t1 + G0 + b1)
    k_prop_w<<<pb128, 256, 0, stream>>>(G + 3 * GS, G + 2 * GS, nullptr, 0,
                                        csr, rowst, rowend, t2, N);
    k_prop_w<<<pb128, 256, 0, stream>>>(t2, G + 1 * GS, nullptr, 0,
                                        csr, rowst, rowend, t1, N);
    k_prop_w<<<pb128, 256, 0, stream>>>(t1, G + 0 * GS, b1, 1,
                                        csr, rowst, rowend, h, N);

    // ---- layer 2: Gc = h @ [V0|V1|V2|V3] (128 cols), then 32-wide Horner
    k_gemm<0><<<gb, 256, 0, stream>>>(h, Bp2, Gc, GS, 1, N);
    k_prop_q<<<pb32, 256, 0, stream>>>(Gc, 192, 0, Gc + 64, nullptr,
                                       csr, rowst, rowend, s1, nullptr, N);
    k_prop_q<<<pb32, 256, 0, stream>>>(s1, 0, 2, Gc + 32, nullptr,
                                       csr, rowst, rowend, s2, nullptr, N);
    k_prop_q<<<pb32, 256, 0, stream>>>(s2, 0, 2, Gc, b2,
                                       csr, rowst, rowend, nullptr, (float*)d_out, N);
}